// Round 1
// baseline (4149.292 us; speedup 1.0000x reference)
//
#include <hip/hip_runtime.h>

// LSTM S=512 B=64 I=256 H=512, gates order f,i,o,g (4H=2048 cols).
// Strategy: persistent-register weights, fused [x_t|h] @ W recurrent GEMM,
// one wave owns 16 batch rows x 16 hidden units across all 4 gates,
// hand-rolled device-wide barrier once per timestep.

#define S_LEN 512
#define NBLK  128

typedef __attribute__((ext_vector_type(8))) __bf16 bf16x8;
typedef __attribute__((ext_vector_type(4))) float  f32x4;

// workspace layout (bytes)
#define OFF_W    ((size_t)0)          // swizzled W: 32*4*24*64*8 bf16 = 3,145,728
#define OFF_BIAS ((size_t)3145728)    // 2048 f32 = 8192
#define OFF_X    ((size_t)4194304)    // x bf16: 512*64*256*2 = 16,777,216
#define OFF_H    ((size_t)20971520)   // h double buffer: 2*64*512*2 = 131072
#define OFF_CNT  ((size_t)21102592)   // 512 int barrier counters = 2048

// ---- prelude: x fp32 -> bf16 (4 elems/thread, 8.4M elems) ----
__global__ void k_conv_x(const float* __restrict__ x, __bf16* __restrict__ xb) {
  int i = blockIdx.x * 256 + threadIdx.x;      // 2,097,152 threads exactly
  float4 v = ((const float4*)x)[i];
  union { __bf16 b[4]; uint2 u; } p;
  p.b[0] = (__bf16)v.x; p.b[1] = (__bf16)v.y;
  p.b[2] = (__bf16)v.z; p.b[3] = (__bf16)v.w;
  ((uint2*)xb)[i] = p.u;
}

// ---- prelude: W -> bf16, MFMA-B-fragment-swizzled ----
// layout: frag index tid = ((hs*4+g)*24 + kk)*64 + L ; lane L holds 8 bf16:
// W[k = kk*32 + (L>>4)*8 + j][col = hs*16 + (L&15)] ; k<256 -> Wx, else Wh.
__global__ void k_conv_w(const float* __restrict__ wxf, const float* __restrict__ whf,
                         const float* __restrict__ wxi, const float* __restrict__ whi,
                         const float* __restrict__ wxo, const float* __restrict__ who,
                         const float* __restrict__ wxg, const float* __restrict__ whg,
                         __bf16* __restrict__ Wswz) {
  int tid = blockIdx.x * 256 + threadIdx.x;    // 196,608 threads exactly
  int L = tid & 63;
  int q = tid >> 6;
  int kk = q % 24;
  int q2 = q / 24;
  int g  = q2 & 3;
  int hs = q2 >> 2;
  const float* Wx = (g == 0) ? wxf : (g == 1) ? wxi : (g == 2) ? wxo : wxg;
  const float* Wh = (g == 0) ? whf : (g == 1) ? whi : (g == 2) ? who : whg;
  int col = hs * 16 + (L & 15);
  int k0  = kk * 32 + (L >> 4) * 8;
  union { __bf16 b[8]; uint4 u; } p;
#pragma unroll
  for (int j = 0; j < 8; ++j) {
    int k = k0 + j;
    float v = (k < 256) ? Wx[k * 512 + col] : Wh[(k - 256) * 512 + col];
    p.b[j] = (__bf16)v;
  }
  ((uint4*)Wswz)[tid] = p.u;
}

// ---- prelude: combined bias b = bx + bh, layout [gate][512] ----
__global__ void k_conv_bias(const float* __restrict__ bxf, const float* __restrict__ bhf,
                            const float* __restrict__ bxi, const float* __restrict__ bhi,
                            const float* __restrict__ bxo, const float* __restrict__ bho,
                            const float* __restrict__ bxg, const float* __restrict__ bhg,
                            float* __restrict__ bc) {
  int n = blockIdx.x * 256 + threadIdx.x;      // 2048 exactly
  int g = n >> 9, h = n & 511;
  const float* bx = (g == 0) ? bxf : (g == 1) ? bxi : (g == 2) ? bxo : bxg;
  const float* bh = (g == 0) ? bhf : (g == 1) ? bhi : (g == 2) ? bho : bhg;
  bc[n] = bx[h] + bh[h];
}

__device__ __forceinline__ float sigm(float x) { return 1.f / (1.f + __expf(-x)); }
__device__ __forceinline__ float tanh_f(float x) { return 1.f - 2.f / (1.f + __expf(2.f * x)); }

// ---- main recurrent kernel ----
// block (mt, hs): mt = batch tile (16 rows), hs = hidden slice (16 units).
// wave0: K=[0,384) (x 0..256 + h 0..128); wave1: K=[384,768) (h 128..512).
// Partial sums reduced through LDS; wave1 does gates/c/h + output stores.
__global__ __launch_bounds__(128, 1) void lstm_seq(
    const __bf16* __restrict__ Wswz, const float* __restrict__ bias,
    const __bf16* __restrict__ xb, __bf16* __restrict__ hb,
    int* __restrict__ cnt, float* __restrict__ out) {
  const int tid  = threadIdx.x;
  const int w    = tid >> 6;
  const int L    = tid & 63;
  const int quad = L >> 4;
  const int lc   = L & 15;
  const int mt   = blockIdx.x & 3;
  const int hs   = blockIdx.x >> 2;

  __shared__ f32x4 red[4][64];

  // persistent weight fragments: 12 K-steps x 4 gates = 192 VGPRs
  bf16x8 Wf[12][4];
  {
    const uint4* wp = (const uint4*)Wswz;
#pragma unroll
    for (int g = 0; g < 4; ++g)
#pragma unroll
      for (int kkl = 0; kkl < 12; ++kkl) {
        int kk = w * 12 + kkl;
        uint4 u = wp[(((size_t)(hs * 4 + g) * 24 + kk) << 6) + L];
        Wf[kkl][g] = __builtin_bit_cast(bf16x8, u);
      }
  }
  float bsv[4];
#pragma unroll
  for (int g = 0; g < 4; ++g) bsv[g] = bias[g * 512 + hs * 16 + lc];

  const int row = mt * 16 + lc;              // A-row this lane loads
  const __bf16* px = xb + (size_t)row * 256 + quad * 8;
  const __bf16* ph0 = hb + (size_t)row * 512 + quad * 8;
  const __bf16* ph1 = ph0 + 32768;

  f32x4 cst = {0.f, 0.f, 0.f, 0.f};          // cell state (wave1 only)

  for (int t = 0; t < S_LEN; ++t) {
    const __bf16* rd = (t & 1) ? ph1 : ph0;
    bf16x8 Af[12];
    if (w == 0) {
#pragma unroll
      for (int kkl = 0; kkl < 8; ++kkl)
        Af[kkl] = __builtin_bit_cast(bf16x8, *(const uint4*)(px + kkl * 32));
#pragma unroll
      for (int kkl = 8; kkl < 12; ++kkl)
        Af[kkl] = __builtin_bit_cast(bf16x8, *(const uint4*)(rd + (kkl - 8) * 32));
    } else {
#pragma unroll
      for (int kkl = 0; kkl < 12; ++kkl)
        Af[kkl] = __builtin_bit_cast(bf16x8, *(const uint4*)(rd + 128 + kkl * 32));
    }

    f32x4 acc[4] = {{0,0,0,0},{0,0,0,0},{0,0,0,0},{0,0,0,0}};
#pragma unroll
    for (int kkl = 0; kkl < 12; ++kkl)
#pragma unroll
      for (int g = 0; g < 4; ++g)
        acc[g] = __builtin_amdgcn_mfma_f32_16x16x32_bf16(Af[kkl], Wf[kkl][g], acc[g], 0, 0, 0);

    if (w == 0) {
#pragma unroll
      for (int g = 0; g < 4; ++g) red[g][L] = acc[g];
    }
    __syncthreads();

    if (w == 1) {
      __bf16* wr = hb + ((size_t)((t + 1) & 1)) * 32768;
#pragma unroll
      for (int g = 0; g < 4; ++g) acc[g] += red[g][L];
      float* oseq = out + (size_t)t * 64 * 512;
      const int col = hs * 16 + lc;
#pragma unroll
      for (int r = 0; r < 4; ++r) {
        float fg = sigm(acc[0][r] + bsv[0]);
        float ig = sigm(acc[1][r] + bsv[1]);
        float og = sigm(acc[2][r] + bsv[2]);
        float gg = tanh_f(acc[3][r] + bsv[3]);
        float cn = fg * cst[r] + ig * gg;
        cst[r] = cn;
        float hv = og * tanh_f(cn);
        int orow = mt * 16 + quad * 4 + r;
        oseq[orow * 512 + col] = hv;
        wr[orow * 512 + col] = (__bf16)hv;
        if (t == S_LEN - 1) {
          out[16777216 + orow * 512 + col] = hv;               // final h
          out[16777216 + 32768 + orow * 512 + col] = cn;       // final c
        }
      }
    }

    // device-wide barrier: per-step counter, release add + acquire spin.
    if (tid == 64) {   // wave1 lane0: its release drains this wave's h stores
      __hip_atomic_fetch_add(&cnt[t], 1, __ATOMIC_RELEASE, __HIP_MEMORY_SCOPE_AGENT);
      while (__hip_atomic_load(&cnt[t], __ATOMIC_ACQUIRE, __HIP_MEMORY_SCOPE_AGENT) < NBLK)
        __builtin_amdgcn_s_sleep(1);
    }
    __syncthreads();
    px += 64 * 256;
  }
}

extern "C" void kernel_launch(void* const* d_in, const int* in_sizes, int n_in,
                              void* d_out, int out_size, void* d_ws, size_t ws_size,
                              hipStream_t stream) {
  char* ws = (char*)d_ws;
  __bf16* Wswz = (__bf16*)(ws + OFF_W);
  float*  bias = (float*)(ws + OFF_BIAS);
  __bf16* xb   = (__bf16*)(ws + OFF_X);
  __bf16* hb   = (__bf16*)(ws + OFF_H);
  int*    cnt  = (int*)(ws + OFF_CNT);

  // zero h double-buffer + barrier counters (ws is poisoned 0xAA each call)
  hipMemsetAsync(ws + OFF_H, 0, 131072 + 2048, stream);

  k_conv_x<<<8192, 256, 0, stream>>>((const float*)d_in[0], xb);
  k_conv_w<<<768, 256, 0, stream>>>(
      (const float*)d_in[1],  (const float*)d_in[3],    // f: Wx, Wh
      (const float*)d_in[5],  (const float*)d_in[7],    // i
      (const float*)d_in[9],  (const float*)d_in[11],   // o
      (const float*)d_in[13], (const float*)d_in[15],   // g
      Wswz);
  k_conv_bias<<<8, 256, 0, stream>>>(
      (const float*)d_in[2],  (const float*)d_in[4],
      (const float*)d_in[6],  (const float*)d_in[8],
      (const float*)d_in[10], (const float*)d_in[12],
      (const float*)d_in[14], (const float*)d_in[16],
      bias);
  lstm_seq<<<NBLK, 128, 0, stream>>>(Wswz, bias, xb, hb, cnt, (float*)d_out);
}

// Round 2
// 2304.614 us; speedup vs baseline: 1.8004x; 1.8004x over previous
//
#include <hip/hip_runtime.h>

// LSTM S=512 B=64 I=256 H=512, gates order f,i,o,g (4H=2048 cols).
// Persistent-register weights, fused [x_t|h] @ W recurrent GEMM.
// R2: relaxed per-mt 32-block barriers + device-scope (IF-coherent) h
// loads/stores instead of full L2 writeback/invalidate per step.

#define S_LEN 512
#define NBLK  128
#define GROUP 32    // blocks per mt-group (same 16 batch rows)

typedef __attribute__((ext_vector_type(8))) __bf16 bf16x8;
typedef __attribute__((ext_vector_type(4))) float  f32x4;

// workspace layout (bytes)
#define OFF_W    ((size_t)0)          // swizzled W: 3,145,728
#define OFF_BIAS ((size_t)3145728)    // 2048 f32
#define OFF_X    ((size_t)4194304)    // x bf16: 16,777,216
#define OFF_H    ((size_t)20971520)   // h double buffer: 2*64*512*2 = 131072
#define OFF_CNT  ((size_t)21102592)   // 512*4 int barrier counters = 8192

// ---- prelude: x fp32 -> bf16 ----
__global__ void k_conv_x(const float* __restrict__ x, __bf16* __restrict__ xb) {
  int i = blockIdx.x * 256 + threadIdx.x;      // 2,097,152 threads exactly
  float4 v = ((const float4*)x)[i];
  union { __bf16 b[4]; uint2 u; } p;
  p.b[0] = (__bf16)v.x; p.b[1] = (__bf16)v.y;
  p.b[2] = (__bf16)v.z; p.b[3] = (__bf16)v.w;
  ((uint2*)xb)[i] = p.u;
}

// ---- prelude: W -> bf16, MFMA-B-fragment-swizzled ----
// frag tid = ((hs*4+g)*24 + kk)*64 + L ; lane L holds 8 bf16:
// W[k = kk*32 + (L>>4)*8 + j][col = hs*16 + (L&15)] ; k<256 -> Wx else Wh.
__global__ void k_conv_w(const float* __restrict__ wxf, const float* __restrict__ whf,
                         const float* __restrict__ wxi, const float* __restrict__ whi,
                         const float* __restrict__ wxo, const float* __restrict__ who,
                         const float* __restrict__ wxg, const float* __restrict__ whg,
                         __bf16* __restrict__ Wswz) {
  int tid = blockIdx.x * 256 + threadIdx.x;    // 196,608 threads exactly
  int L = tid & 63;
  int q = tid >> 6;
  int kk = q % 24;
  int q2 = q / 24;
  int g  = q2 & 3;
  int hs = q2 >> 2;
  const float* Wx = (g == 0) ? wxf : (g == 1) ? wxi : (g == 2) ? wxo : wxg;
  const float* Wh = (g == 0) ? whf : (g == 1) ? whi : (g == 2) ? who : whg;
  int col = hs * 16 + (L & 15);
  int k0  = kk * 32 + (L >> 4) * 8;
  union { __bf16 b[8]; uint4 u; } p;
#pragma unroll
  for (int j = 0; j < 8; ++j) {
    int k = k0 + j;
    float v = (k < 256) ? Wx[k * 512 + col] : Wh[(k - 256) * 512 + col];
    p.b[j] = (__bf16)v;
  }
  ((uint4*)Wswz)[tid] = p.u;
}

// ---- prelude: combined bias b = bx + bh, layout [gate][512] ----
__global__ void k_conv_bias(const float* __restrict__ bxf, const float* __restrict__ bhf,
                            const float* __restrict__ bxi, const float* __restrict__ bhi,
                            const float* __restrict__ bxo, const float* __restrict__ bho,
                            const float* __restrict__ bxg, const float* __restrict__ bhg,
                            float* __restrict__ bc) {
  int n = blockIdx.x * 256 + threadIdx.x;      // 2048 exactly
  int g = n >> 9, h = n & 511;
  const float* bx = (g == 0) ? bxf : (g == 1) ? bxi : (g == 2) ? bxo : bxg;
  const float* bh = (g == 0) ? bhf : (g == 1) ? bhi : (g == 2) ? bho : bhg;
  bc[n] = bx[h] + bh[h];
}

__device__ __forceinline__ float sigm(float x) { return 1.f / (1.f + __expf(-x)); }
__device__ __forceinline__ float tanh_f(float x) { return 1.f - 2.f / (1.f + __expf(2.f * x)); }

// device-scope (IF-coherent, L2-bypass) 16B h-fragment load as 2x b64 atomics
__device__ __forceinline__ bf16x8 load_h8(const __bf16* p) {
  union { unsigned long long q[2]; bf16x8 v; } u;
  u.q[0] = __hip_atomic_load((const unsigned long long*)p,       __ATOMIC_RELAXED, __HIP_MEMORY_SCOPE_AGENT);
  u.q[1] = __hip_atomic_load((const unsigned long long*)(p + 4), __ATOMIC_RELAXED, __HIP_MEMORY_SCOPE_AGENT);
  return u.v;
}

// ---- main recurrent kernel ----
// block (mt, hs): mt = batch tile (16 rows), hs = hidden slice (16 units).
// wave0: K=[0,384) (x + h[0:128)); wave1: K=[384,768) (h[128:512)).
// Partial sums reduced through LDS; wave1 does gates/c/h + output stores.
// Per-step barrier only among the 32 blocks sharing mt.
__global__ __launch_bounds__(128, 1) void lstm_seq(
    const __bf16* __restrict__ Wswz, const float* __restrict__ bias,
    const __bf16* __restrict__ xb, __bf16* __restrict__ hb,
    int* __restrict__ cnt, float* __restrict__ out) {
  const int tid  = threadIdx.x;
  const int w    = tid >> 6;
  const int L    = tid & 63;
  const int quad = L >> 4;
  const int lc   = L & 15;
  const int mt   = blockIdx.x & 3;
  const int hs   = blockIdx.x >> 2;

  __shared__ f32x4 red[4][64];

  // persistent weight fragments: 12 K-steps x 4 gates
  bf16x8 Wf[12][4];
  {
    const uint4* wp = (const uint4*)Wswz;
#pragma unroll
    for (int g = 0; g < 4; ++g)
#pragma unroll
      for (int kkl = 0; kkl < 12; ++kkl) {
        int kk = w * 12 + kkl;
        uint4 u = wp[(((size_t)(hs * 4 + g) * 24 + kk) << 6) + L];
        Wf[kkl][g] = __builtin_bit_cast(bf16x8, u);
      }
  }
  float bsv[4];
#pragma unroll
  for (int g = 0; g < 4; ++g) bsv[g] = bias[g * 512 + hs * 16 + lc];

  const int row = mt * 16 + lc;              // A-row this lane loads
  const __bf16* px = xb + (size_t)row * 256 + quad * 8;
  const __bf16* ph0 = hb + (size_t)row * 512 + quad * 8;
  const __bf16* ph1 = ph0 + 32768;

  f32x4 cst = {0.f, 0.f, 0.f, 0.f};          // cell state (wave1 only)

  for (int t = 0; t < S_LEN; ++t) {
    const __bf16* rd = (t & 1) ? ph1 : ph0;
    bf16x8 Af[12];

    // x prefetch under the barrier wait (plain cached loads, wave0 only)
    if (w == 0) {
#pragma unroll
      for (int kkl = 0; kkl < 8; ++kkl)
        Af[kkl] = __builtin_bit_cast(bf16x8, *(const uint4*)(px + kkl * 32));
    }

    // wait for previous step's producers (relaxed: no cache maintenance)
    if (t > 0) {
      const int* ca = &cnt[(t - 1) * 4 + mt];
      while (__hip_atomic_load(ca, __ATOMIC_RELAXED, __HIP_MEMORY_SCOPE_AGENT) < GROUP) {}
    }

    // h fragment loads, device-scope (bypass stale L2, hit IF)
    if (w == 0) {
#pragma unroll
      for (int kkl = 8; kkl < 12; ++kkl)
        Af[kkl] = load_h8(rd + (kkl - 8) * 32);
    } else {
#pragma unroll
      for (int kkl = 0; kkl < 12; ++kkl)
        Af[kkl] = load_h8(rd + 128 + kkl * 32);
    }

    f32x4 acc[4] = {{0,0,0,0},{0,0,0,0},{0,0,0,0},{0,0,0,0}};
#pragma unroll
    for (int kkl = 0; kkl < 12; ++kkl)
#pragma unroll
      for (int g = 0; g < 4; ++g)
        acc[g] = __builtin_amdgcn_mfma_f32_16x16x32_bf16(Af[kkl], Wf[kkl][g], acc[g], 0, 0, 0);

    if (w == 0) {
#pragma unroll
      for (int g = 0; g < 4; ++g) red[g][L] = acc[g];
    }
    __syncthreads();

    if (w == 1) {
      __bf16* wr = hb + ((size_t)((t + 1) & 1)) * 32768;
#pragma unroll
      for (int g = 0; g < 4; ++g) acc[g] += red[g][L];
      float* oseq = out + (size_t)t * 64 * 512;
      const int col = hs * 16 + lc;
#pragma unroll
      for (int r = 0; r < 4; ++r) {
        float fg = sigm(acc[0][r] + bsv[0]);
        float ig = sigm(acc[1][r] + bsv[1]);
        float og = sigm(acc[2][r] + bsv[2]);
        float gg = tanh_f(acc[3][r] + bsv[3]);
        float cn = fg * cst[r] + ig * gg;
        cst[r] = cn;
        float hv = og * tanh_f(cn);
        int orow = mt * 16 + quad * 4 + r;
        oseq[orow * 512 + col] = hv;
        // device-scope write-through h store (no L2 writeback needed later)
        unsigned short hbits = __builtin_bit_cast(unsigned short, (__bf16)hv);
        __hip_atomic_store((unsigned short*)&wr[orow * 512 + col], hbits,
                           __ATOMIC_RELAXED, __HIP_MEMORY_SCOPE_AGENT);
        if (t == S_LEN - 1) {
          out[16777216 + orow * 512 + col] = hv;               // final h
          out[16777216 + 32768 + orow * 512 + col] = cn;       // final c
        }
      }
      // arrive: drain this wave's h stores to the coherence point, then
      // relaxed add (release ordering = vmcnt(0) since stores are write-through)
      if (tid == 64) {
        asm volatile("s_waitcnt vmcnt(0)" ::: "memory");
        __hip_atomic_fetch_add(&cnt[t * 4 + mt], 1, __ATOMIC_RELAXED,
                               __HIP_MEMORY_SCOPE_AGENT);
      }
    }
    px += 64 * 256;
  }
}

extern "C" void kernel_launch(void* const* d_in, const int* in_sizes, int n_in,
                              void* d_out, int out_size, void* d_ws, size_t ws_size,
                              hipStream_t stream) {
  char* ws = (char*)d_ws;
  __bf16* Wswz = (__bf16*)(ws + OFF_W);
  float*  bias = (float*)(ws + OFF_BIAS);
  __bf16* xb   = (__bf16*)(ws + OFF_X);
  __bf16* hb   = (__bf16*)(ws + OFF_H);
  int*    cnt  = (int*)(ws + OFF_CNT);

  // zero h double-buffer + barrier counters (ws is poisoned 0xAA each call)
  hipMemsetAsync(ws + OFF_H, 0, 131072 + 8192, stream);

  k_conv_x<<<8192, 256, 0, stream>>>((const float*)d_in[0], xb);
  k_conv_w<<<768, 256, 0, stream>>>(
      (const float*)d_in[1],  (const float*)d_in[3],    // f: Wx, Wh
      (const float*)d_in[5],  (const float*)d_in[7],    // i
      (const float*)d_in[9],  (const float*)d_in[11],   // o
      (const float*)d_in[13], (const float*)d_in[15],   // g
      Wswz);
  k_conv_bias<<<8, 256, 0, stream>>>(
      (const float*)d_in[2],  (const float*)d_in[4],
      (const float*)d_in[6],  (const float*)d_in[8],
      (const float*)d_in[10], (const float*)d_in[12],
      (const float*)d_in[14], (const float*)d_in[16],
      bias);
  lstm_seq<<<NBLK, 128, 0, stream>>>(Wswz, bias, xb, hb, cnt, (float*)d_out);
}